// Round 9
// baseline (462.511 us; speedup 1.0000x reference)
//
#include <hip/hip_runtime.h>
#include <math.h>

// Problem constants (fixed by setup_inputs)
#define BB 16
#define CC 96
#define HH 112
#define WW 112
#define HO 56
#define WO 56
#define LL (HO*WO)       // 3136
#define CO 192
#define CKD 384          // C*K
#define NPIX (BB*LL)     // 50176
#define PADROW 388       // LDS row pad for sampled[32][384]

// ws layout (floats): ssum=+16 (192), ssqs=+208 (192), scale=+400, shift=+592
#define WS_SSUM  16
#define WS_SSQS  208
#define WS_SCALE 400
#define WS_SHIFT 592

// -------- K0: zero the stats accumulators --------
__global__ void k_zero(float* __restrict__ ws) {
    int t = threadIdx.x;
    if (t < 384) ws[WS_SSUM + t] = 0.f;
}

// ---- K2: fused offset-conv + bilinear sample + GEMM + stats + y store ----
__global__ __launch_bounds__(256) void k_main(
    const float* __restrict__ x,      // [B][C][H][W]
    const float* __restrict__ w_off,  // [8][C][2][2]
    const float* __restrict__ b_off,  // [8]
    const float* __restrict__ w_def,  // [CO][C][4]
    float* __restrict__ yout,         // d_out fp32 [B][L][CO] (pre-BN y)
    float* __restrict__ ws)
{
    __shared__ float sm[32 * PADROW];    // 49664 B
    __shared__ float soff[32 * 8];       // [pix][och] conv-offset outputs
    const int tid = threadIdx.x;
    const int b  = blockIdx.y;
    const int l0 = blockIdx.x * 32;

    const int pair = tid >> 1;   // 0..127 = (pix, k)
    const int half = tid & 1;
    const int pix = pair >> 2;
    const int k   = pair & 3;
    const int l   = l0 + pix;
    const int oy = l / WO, ox = l % WO;
    const int iy = oy * 2, ix = ox * 2;

    // ---- Phase 0: offset conv. thread computes channel och=2k+half ----
    {
        const int och = 2 * k + half;
        float d = b_off[och];
        const float* xb = x + ((size_t)b * CC) * (HH * WW) + (size_t)iy * WW + ix;
        const float* wb = w_off + (size_t)och * (CC * 4);
        for (int c = 0; c < CC; ++c) {
            const float* xp = xb + (size_t)c * (HH * WW);
            float4 a = *(const float4*)(wb + c * 4);
            d += xp[0] * a.x + xp[1] * a.y + xp[WW] * a.z + xp[WW + 1] * a.w;
        }
        soff[pix * 8 + och] = d;
    }
    __syncthreads();

    // ---- Phase A: bilinear sampling 32 pixels x 384 (c*4+k) into LDS ----
    {
        const int ky = k >> 1, kx = k & 1;
        float fy = (float)(iy + ky) + soff[pix * 8 + 2 * k];
        float fx = (float)(ix + kx) + soff[pix * 8 + 2 * k + 1];
        float y0f = floorf(fy), x0f = floorf(fx);
        int y0 = (int)y0f, x0 = (int)x0f;
        float wy1 = fy - y0f, wx1 = fx - x0f;
        float wy0 = 1.f - wy1, wx0 = 1.f - wx1;
        int y1 = y0 + 1, x1 = x0 + 1;
        bool vy0 = (y0 >= 0) && (y0 <= HH - 1);
        bool vy1 = (y1 >= 0) && (y1 <= HH - 1);
        bool vx0 = (x0 >= 0) && (x0 <= WW - 1);
        bool vx1 = (x1 >= 0) && (x1 <= WW - 1);
        int cy0 = min(max(y0, 0), HH - 1), cy1 = min(max(y1, 0), HH - 1);
        int cx0 = min(max(x0, 0), WW - 1), cx1 = min(max(x1, 0), WW - 1);
        float w00 = (vy0 && vx0) ? wy0 * wx0 : 0.f;
        float w01 = (vy0 && vx1) ? wy0 * wx1 : 0.f;
        float w10 = (vy1 && vx0) ? wy1 * wx0 : 0.f;
        float w11 = (vy1 && vx1) ? wy1 * wx1 : 0.f;
        int i00 = cy0 * WW + cx0, i01 = cy0 * WW + cx1;
        int i10 = cy1 * WW + cx0, i11 = cy1 * WW + cx1;
        const int cbeg = half * 48;
        const float* xc = x + (size_t)b * CC * (HH * WW) + (size_t)cbeg * (HH * WW);
        float* dst = &sm[pix * PADROW + k];
        for (int c = 0; c < 48; ++c) {
            float v = w00 * xc[i00] + w01 * xc[i01]
                    + w10 * xc[i10] + w11 * xc[i11];
            dst[(cbeg + c) * 4] = v;
            xc += HH * WW;
        }
    }
    __syncthreads();

    // ---- Phase B: GEMM [32 x 384] * [384 x 192] ----
    const int pg = tid & 7;    // pixels pg*4 .. pg*4+3
    const int og = tid >> 3;   // outputs og*6 .. og*6+5
    float acc[4][6];
    #pragma unroll
    for (int p = 0; p < 4; ++p)
        #pragma unroll
        for (int j = 0; j < 6; ++j) acc[p][j] = 0.f;

    for (int ck = 0; ck < CKD; ck += 4) {
        float4 s[4];
        #pragma unroll
        for (int p = 0; p < 4; ++p)
            s[p] = *(const float4*)&sm[(pg * 4 + p) * PADROW + ck];
        #pragma unroll
        for (int j = 0; j < 6; ++j) {
            float4 wv = *(const float4*)&w_def[(size_t)(og * 6 + j) * CKD + ck];
            #pragma unroll
            for (int p = 0; p < 4; ++p)
                acc[p][j] += s[p].x * wv.x + s[p].y * wv.y + s[p].z * wv.z + s[p].w * wv.w;
        }
    }
    __syncthreads();

    // ---- Phase C: stage y in LDS, stats, coalesced fp32 store ----
    float* ys = sm;  // 32*193 floats, reuse
    #pragma unroll
    for (int p = 0; p < 4; ++p)
        #pragma unroll
        for (int j = 0; j < 6; ++j)
            ys[(pg * 4 + p) * 193 + og * 6 + j] = acc[p][j];
    __syncthreads();

    if (tid < CO) {
        float s = 0.f, q = 0.f;
        #pragma unroll 8
        for (int p = 0; p < 32; ++p) {
            float v = ys[p * 193 + tid];
            s += v; q += v * v;
        }
        atomicAdd(&ws[WS_SSUM + tid], s);
        atomicAdd(&ws[WS_SSQS + tid], q);
    }

    size_t base = ((size_t)b * LL + l0) * CO;
    for (int i = tid; i < 32 * CO; i += 256) {
        int pp = i / CO, o = i % CO;
        yout[base + i] = ys[pp * 193 + o];
    }
}

// ------------- K2.5: per-channel scale/shift from batch stats -------------
__global__ void k_stats(const float* __restrict__ gamma,
                        const float* __restrict__ beta,
                        float* __restrict__ ws)
{
    int o = threadIdx.x;
    if (o < CO) {
        float n = (float)NPIX;
        float mu = ws[WS_SSUM + o] / n;
        float var = ws[WS_SSQS + o] / n - mu * mu;
        float sc = gamma[o] * rsqrtf(fmaxf(var, 0.f) + 1e-5f);
        ws[WS_SCALE + o] = sc;
        ws[WS_SHIFT + o] = beta[o] - mu * sc;
    }
}

// ---------------- K3: in-place fp32 BN + exact GELU over d_out ----------------
__global__ __launch_bounds__(256) void k_bn_gelu(
    float* __restrict__ out,          // fp32, in/out, [B][L][CO]
    const float* __restrict__ ws)
{
    long long gid = (long long)blockIdx.x * 256 + threadIdx.x;
    long long i4 = gid * 4;
    if (i4 >= (long long)NPIX * CO) return;
    int o0 = (int)(i4 % CO);          // 4 | 192 -> quad stays in-channel-run
    float4* p = (float4*)(out + i4);
    float4 v = *p;
    float f[4] = { v.x, v.y, v.z, v.w };
    #pragma unroll
    for (int j = 0; j < 4; ++j) {
        float z = ws[WS_SCALE + o0 + j] * f[j] + ws[WS_SHIFT + o0 + j];
        f[j] = 0.5f * z * (1.f + erff(z * 0.70710678118654752f));
    }
    v.x = f[0]; v.y = f[1]; v.z = f[2]; v.w = f[3];
    *p = v;
}

extern "C" void kernel_launch(void* const* d_in, const int* in_sizes, int n_in,
                              void* d_out, int out_size, void* d_ws, size_t ws_size,
                              hipStream_t stream)
{
    // Bind by size signature (robust to scalar h/w presence):
    const float *x = nullptr, *w_off = nullptr, *b_off = nullptr;
    const float *w_def = nullptr, *gamma = nullptr, *beta = nullptr;
    for (int i = 0; i < n_in; ++i) {
        int s = in_sizes[i];
        if      (s == 19267584) x     = (const float*)d_in[i];
        else if (s == 3072)     w_off = (const float*)d_in[i];
        else if (s == 8)        b_off = (const float*)d_in[i];
        else if (s == 73728)    w_def = (const float*)d_in[i];
        else if (s == 192) { if (!gamma) gamma = (const float*)d_in[i];
                             else        beta  = (const float*)d_in[i]; }
    }
    if (!x || !w_off || !b_off || !w_def || !gamma || !beta) {
        x = (const float*)d_in[0]; w_off = (const float*)d_in[3];
        b_off = (const float*)d_in[4]; w_def = (const float*)d_in[5];
        gamma = (const float*)d_in[6]; beta = (const float*)d_in[7];
    }

    float* ws = (float*)d_ws;                  // ~3.1 KB used
    float* out = (float*)d_out;                // FP32 output

    k_zero<<<1, 384, 0, stream>>>(ws);
    k_main<<<dim3(LL/32, BB), 256, 0, stream>>>(x, w_off, b_off, w_def, out, ws);
    k_stats<<<1, 256, 0, stream>>>(gamma, beta, ws);
    k_bn_gelu<<<dim3((int)(((long long)NPIX*CO/4 + 255) / 256)), 256, 0, stream>>>(out, ws);
}